// Round 16
// baseline (188.826 us; speedup 1.0000x reference)
//
#include <hip/hip_runtime.h>

typedef float f32x4 __attribute__((ext_vector_type(4)));
typedef short s16x8 __attribute__((ext_vector_type(8)));
typedef short s16x4 __attribute__((ext_vector_type(4)));

#define BSTRIDE 9216   // fixed per-bucket capacity in packed[]; E*512/n=8192 expected, +11 sigma

__device__ __forceinline__ unsigned short f2bf(float f) {
    unsigned u = __builtin_bit_cast(unsigned, f);
    unsigned r = (u + 0x7FFFu + ((u >> 16) & 1u)) >> 16;
    return (unsigned short)r;
}
__device__ __forceinline__ float bf2f(unsigned short h) {
    unsigned u = ((unsigned)h) << 16;
    return __builtin_bit_cast(float, u);
}
__device__ __forceinline__ float bflo(unsigned u) {
    return __builtin_bit_cast(float, u << 16);
}
__device__ __forceinline__ float bfhi(unsigned u) {
    return __builtin_bit_cast(float, u & 0xffff0000u);
}

// ---------------- weight fragment packing (+ gcursor zero) ----------------
__global__ __launch_bounds__(256)
void pack_frags(const float* __restrict__ W1l, const float* __restrict__ W1r,
                const float* __restrict__ W2l, const float* __restrict__ W2r,
                const float* __restrict__ Wo,
                short* __restrict__ PH1, short* __restrict__ PL1,
                short* __restrict__ PH2, short* __restrict__ PL2,
                short* __restrict__ PHo, short* __restrict__ PLo,
                int* __restrict__ gcursor, int nbkt)
{
    if (blockIdx.x == 0)
        for (int i = threadIdx.x; i < nbkt; i += 256) gcursor[i] = 0;
    const int tot = 2048 + 1024 + 896;
    for (int e = blockIdx.x * 256 + threadIdx.x; e < tot; e += gridDim.x * 256) {
        int lane, f, k0, c, stride;
        const float* W;
        short *PH, *PL;
        int idx;
        if (e < 2048) {
            idx = e; lane = e & 63; f = e >> 6;
            int kt = f & 3, ct = (f >> 2) & 3, m = f >> 4;
            W = m ? W1r : W1l; PH = PH1; PL = PL1;
            k0 = kt * 32 + ((lane >> 4) << 3);
            c  = ct * 16 + (lane & 15);
            stride = 64;
        } else if (e < 3072) {
            int e2 = e - 2048;
            idx = e2; lane = e2 & 63; f = e2 >> 6;
            int kt = f & 1, ct = (f >> 1) & 3, m = f >> 3;
            W = m ? W2r : W2l; PH = PH2; PL = PL2;
            k0 = kt * 32 + ((lane >> 4) << 3);
            c  = ct * 16 + (lane & 15);
            stride = 64;
        } else {
            int eo = e - 3072;
            idx = eo; lane = eo & 63; f = eo >> 6;
            int kt = f & 1, ct = f >> 1;
            W = Wo; PH = PHo; PL = PLo;
            k0 = kt * 32 + ((lane >> 4) << 3);
            c  = ct * 16 + (lane & 15);
            stride = 112;
        }
        short h[8], l[8];
        #pragma unroll
        for (int j = 0; j < 8; ++j) {
            float v = W[(size_t)(k0 + j) * stride + c];
            unsigned short hb = f2bf(v);
            h[j] = (short)hb;
            l[j] = (short)f2bf(v - bf2f(hb));
        }
        #pragma unroll
        for (int j = 0; j < 8; ++j) { PH[idx * 8 + j] = h[j]; PL[idx * 8 + j] = l[j]; }
    }
}

// ------- fused: GEMM1 (blocks [0,gemmBlocks)) + bucket_scatter (rest) -------
// Scatter: 2048 edges/block (4/thread) into fixed-stride bucket segments.
// GEMM1 = x @ {W1l,W1r}, f32 in (3-term hi/lo), bf16 out.
__global__ __launch_bounds__(512)
void fused_gemm1_scatter(const float* __restrict__ X, const short* __restrict__ PH,
                         const short* __restrict__ PL, unsigned short* __restrict__ Yl,
                         unsigned short* __restrict__ Yr, int n,
                         const int* __restrict__ src, const int* __restrict__ dst,
                         int* __restrict__ gcursor, int* __restrict__ packed,
                         int E, int B, int gemmBlocks)
{
    __shared__ unsigned short sT[8][16 * 72];
    __shared__ int lh[256];
    __shared__ int lbase[256];

    if ((int)blockIdx.x >= gemmBlocks) {
        // ---- bucket scatter (2048 edges/block, 4/thread) ----
        for (int i = threadIdx.x; i < B; i += 512) lh[i] = 0;
        __syncthreads();
        long base = (long)(blockIdx.x - gemmBlocks) * 2048;
        int bkt[4], rnk[4], pk[4];
        #pragma unroll
        for (int j = 0; j < 4; ++j) {
            long e = base + j * 512 + threadIdx.x;
            if (e < E) {
                int d = dst[e], s = src[e];
                bkt[j] = d >> 9;
                pk[j]  = (s << 9) | (d & 511);
                rnk[j] = atomicAdd(&lh[bkt[j]], 1);
            } else bkt[j] = -1;
        }
        __syncthreads();
        for (int i = threadIdx.x; i < B; i += 512) {
            int v = lh[i];
            lbase[i] = v ? atomicAdd(&gcursor[i], v) : 0;
        }
        __syncthreads();
        #pragma unroll
        for (int j = 0; j < 4; ++j)
            if (bkt[j] >= 0)
                packed[(size_t)bkt[j] * BSTRIDE + lbase[bkt[j]] + rnk[j]] = pk[j];
        return;
    }

    // ---- GEMM1 ----
    constexpr int K = 128, NKT = 4;
    const int lane = threadIdx.x & 63;
    const int wid  = threadIdx.x >> 6;
    const long ntile = ((long)n + 15) >> 4;
    long t = (long)blockIdx.x * 8 + wid;
    if (t >= ntile) return;
    const long rbase = t << 4;
    long arow = rbase + (lane & 15);
    if (arow >= n) arow = n - 1;
    const int koff = (lane >> 4) << 3;
    const float* xr = X + arow * K + koff;

    s16x8 Bh[NKT], Bl[NKT];
    #pragma unroll
    for (int kt = 0; kt < NKT; ++kt) {
        f32x4 a0 = *(const f32x4*)(xr + kt * 32);
        f32x4 a1 = *(const f32x4*)(xr + kt * 32 + 4);
        s16x8 h, l;
        #pragma unroll
        for (int j = 0; j < 4; ++j) {
            float v = a0[j]; unsigned short hb = f2bf(v);
            h[j] = (short)hb; l[j] = (short)f2bf(v - bf2f(hb));
            float v2 = a1[j]; unsigned short hb2 = f2bf(v2);
            h[4 + j] = (short)hb2; l[4 + j] = (short)f2bf(v2 - bf2f(hb2));
        }
        Bh[kt] = h; Bl[kt] = l;
    }

    f32x4 acc[2][4];
    #pragma unroll
    for (int m = 0; m < 2; ++m)
        #pragma unroll
        for (int ct = 0; ct < 4; ++ct) acc[m][ct] = (f32x4)(0.f);

    #pragma unroll
    for (int m = 0; m < 2; ++m)
    #pragma unroll
    for (int ct = 0; ct < 4; ++ct)
    #pragma unroll
    for (int kt = 0; kt < NKT; ++kt) {
        const int fidx = ((((m << 2) | ct) * NKT) + kt) * 64 + lane;
        s16x8 Ah = *(const s16x8*)(PH + (size_t)fidx * 8);
        s16x8 Al = *(const s16x8*)(PL + (size_t)fidx * 8);
        acc[m][ct] = __builtin_amdgcn_mfma_f32_16x16x32_bf16(Ah, Bh[kt], acc[m][ct], 0, 0, 0);
        acc[m][ct] = __builtin_amdgcn_mfma_f32_16x16x32_bf16(Al, Bh[kt], acc[m][ct], 0, 0, 0);
        acc[m][ct] = __builtin_amdgcn_mfma_f32_16x16x32_bf16(Ah, Bl[kt], acc[m][ct], 0, 0, 0);
    }

    const int wrow = lane & 15, q4 = (lane >> 4) << 2;
    #pragma unroll
    for (int m = 0; m < 2; ++m) {
        unsigned short* __restrict__ Y = m ? Yr : Yl;
        #pragma unroll
        for (int ct = 0; ct < 4; ++ct) {
            s16x4 pv;
            #pragma unroll
            for (int j = 0; j < 4; ++j) pv[j] = (short)f2bf(acc[m][ct][j]);
            *(s16x4*)&sT[wid][wrow * 72 + ct * 16 + q4] = pv;
        }
        asm volatile("s_waitcnt lgkmcnt(0)" ::: "memory");
        if (rbase + 16 <= (long)n) {
            #pragma unroll
            for (int s = 0; s < 2; ++s) {
                int f = s * 64 + lane;
                s16x8 v = *(const s16x8*)&sT[wid][(f >> 3) * 72 + ((f & 7) << 3)];
                *(s16x8*)&Y[rbase * 64 + (size_t)f * 8] = v;
            }
        } else {
            #pragma unroll
            for (int s = 0; s < 2; ++s) {
                int f = s * 64 + lane;
                s16x8 v = *(const s16x8*)&sT[wid][(f >> 3) * 72 + ((f & 7) << 3)];
                long g = rbase * 64 + (size_t)f * 8;
                #pragma unroll
                for (int jj = 0; jj < 8; ++jj)
                    if (g + jj < (long)n * 64) Y[g + jj] = (unsigned short)v[jj];
            }
        }
        asm volatile("s_waitcnt lgkmcnt(0)" ::: "memory");
    }
}

// per bucket: histogram + in-LDS exclusive scan of PAD8 degrees.
// segment = packed[b*BSTRIDE .. b*BSTRIDE + cnts[b]).
// writes degi (real), rowptrP (bucket-LOCAL positions), partial[b] = bucket total.
__global__ __launch_bounds__(256)
void hist_scan(const int* __restrict__ packed, const int* __restrict__ cnts,
               int* __restrict__ degi, int* __restrict__ rowptrP,
               int* __restrict__ partial, int n)
{
    __shared__ int h[512];
    __shared__ int s[256];
    const int b = blockIdx.x, t = threadIdx.x, nb = b << 9;
    int cnt = n - nb; if (cnt > 512) cnt = 512;
    for (int i = t; i < 512; i += 256) h[i] = 0;
    __syncthreads();
    int bs = b * BSTRIDE, be = bs + cnts[b];
    for (int i = bs + t; i < be; i += 256)
        atomicAdd(&h[packed[i] & 511], 1);
    __syncthreads();
    int e0 = (2 * t     < cnt) ? h[2 * t]     : 0;
    int e1 = (2 * t + 1 < cnt) ? h[2 * t + 1] : 0;
    int p0 = (e0 + 7) & ~7;
    int p1 = (e1 + 7) & ~7;
    int mysum = p0 + p1;
    s[t] = mysum;
    __syncthreads();
    for (int off = 1; off < 256; off <<= 1) {
        int u = (t >= off) ? s[t - off] : 0;
        __syncthreads();
        s[t] += u;
        __syncthreads();
    }
    int excl = s[t] - mysum;
    if (2 * t < cnt)     { degi[nb + 2 * t]     = e0; rowptrP[nb + 2 * t]     = excl; }
    if (2 * t + 1 < cnt) { degi[nb + 2 * t + 1] = e1; rowptrP[nb + 2 * t + 1] = excl + p0; }
    if (t == 255) partial[b] = s[255];
}

// fill + finalize: compute bucket prefix (cooperative sum of partial[0..b)),
// add to rowptrP (write back global), fill csr (byte offsets), dummy-pad,
// write rowptrP[n] (last block), zero dummy feat row (block 0).
__global__ __launch_bounds__(256)
void bucket_fill_final(const int* __restrict__ packed, const int* __restrict__ cnts,
                       const int* __restrict__ partial, int* __restrict__ rowptrP,
                       int* __restrict__ csr, unsigned* __restrict__ Adummy,
                       int n, int nbkt, int dummyOff)
{
    __shared__ int cur[512];
    __shared__ int rs[513];
    __shared__ int red[256];
    const int b = blockIdx.x, t = threadIdx.x, nb = b << 9;
    int cnt = n - nb; if (cnt > 512) cnt = 512;

    // cooperative sum of partial[0..b)
    int loc = 0;
    for (int j = t; j < b; j += 256) loc += partial[j];
    red[t] = loc;
    __syncthreads();
    for (int off = 128; off > 0; off >>= 1) {
        if (t < off) red[t] += red[t + off];
        __syncthreads();
    }
    const int base = red[0];
    const int bend = base + partial[b];

    for (int i = t; i < cnt; i += 256) {
        int v = rowptrP[nb + i] + base;
        rowptrP[nb + i] = v;
        cur[i] = v;
        rs[i] = v;
    }
    if (t == 0) rs[cnt] = bend;
    if (b == nbkt - 1 && t == 0) rowptrP[n] = bend;
    if (b == 0 && t < 32) Adummy[t] = 0u;
    __syncthreads();

    int bs = b * BSTRIDE, be = bs + cnts[b];
    for (int i = bs + t; i < be; i += 256) {
        int p = packed[i];
        int pos = atomicAdd(&cur[p & 511], 1);
        csr[pos] = (p >> 9) << 7;
    }
    __syncthreads();
    for (int i = t; i < cnt; i += 256) {
        int end = rs[i + 1];
        for (int p = cur[i]; p < end; ++p) csr[p] = dummyOff;
    }
}

// ---- pull + fused epilogue, PAD-8 lists, pipelined offsets, 2 rows/wave ----
__global__ __launch_bounds__(256)
void pull_agg_pad(const unsigned short* __restrict__ feat, const int* __restrict__ rowptrP,
                  const int* __restrict__ degi, const int* __restrict__ csrB,
                  const unsigned short* __restrict__ C, const float* __restrict__ bias,
                  unsigned short* __restrict__ H, int n)
{
    const int lane = threadIdx.x & 63;
    const int half = lane >> 5;
    const int c    = lane & 31;
    const int wid  = threadIdx.x >> 6;
    const char* fb = (const char*)feat;
    const int cb   = c << 2;
    const float2 bv = *(const float2*)&bias[c * 2];

    const long w  = (long)blockIdx.x * 4 + wid;
    const long nw = (long)gridDim.x * 4;
    for (long rp = w * 2; rp < n; rp += nw * 2) {
        int2 rr = *(const int2*)&rowptrP[rp];
        int eB = (rp + 1 < n) ? rowptrP[rp + 2] : rr.y;

        const long r = rp + half;
        int dg = 1; unsigned cu = 0;
        if (r < n) {
            dg = degi[r];
            cu = *(const unsigned*)&C[(size_t)r * 64 + (c << 1)];
        }

        int iA = rr.x + (half << 2);
        int iB = rr.y + (half << 2);
        const int endA = rr.y, endB = eB;
        bool dA = iA < endA, dB = iB < endB;
        int4 oA = (int4)(0), oB = (int4)(0);
        if (dA) oA = *(const int4*)&csrB[iA];
        if (dB) oB = *(const int4*)&csrB[iB];

        float a0A = 0.f, a1A = 0.f, a0B = 0.f, a1B = 0.f;
        while (dA | dB) {
            unsigned uA0, uA1, uA2, uA3, uB0, uB1, uB2, uB3;
            if (dA) {
                uA0 = *(const unsigned*)(fb + oA.x + cb);
                uA1 = *(const unsigned*)(fb + oA.y + cb);
                uA2 = *(const unsigned*)(fb + oA.z + cb);
                uA3 = *(const unsigned*)(fb + oA.w + cb);
            }
            if (dB) {
                uB0 = *(const unsigned*)(fb + oB.x + cb);
                uB1 = *(const unsigned*)(fb + oB.y + cb);
                uB2 = *(const unsigned*)(fb + oB.z + cb);
                uB3 = *(const unsigned*)(fb + oB.w + cb);
            }
            int niA = iA + 8, niB = iB + 8;
            bool ndA = niA < endA, ndB = niB < endB;
            int4 tA = oA, tB = oB;
            if (ndA) tA = *(const int4*)&csrB[niA];
            if (ndB) tB = *(const int4*)&csrB[niB];
            if (dA) {
                a0A += bflo(uA0); a1A += bfhi(uA0);
                a0A += bflo(uA1); a1A += bfhi(uA1);
                a0A += bflo(uA2); a1A += bfhi(uA2);
                a0A += bflo(uA3); a1A += bfhi(uA3);
            }
            if (dB) {
                a0B += bflo(uB0); a1B += bfhi(uB0);
                a0B += bflo(uB1); a1B += bfhi(uB1);
                a0B += bflo(uB2); a1B += bfhi(uB2);
                a0B += bflo(uB3); a1B += bfhi(uB3);
            }
            oA = tA; oB = tB; iA = niA; iB = niB; dA = ndA; dB = ndB;
        }

        a0A += __shfl_xor(a0A, 32, 64);
        a1A += __shfl_xor(a1A, 32, 64);
        a0B += __shfl_xor(a0B, 32, 64);
        a1B += __shfl_xor(a1B, 32, 64);

        if (r < n) {
            float m0 = half ? a0B : a0A;
            float m1 = half ? a1B : a1A;
            float d = (float)dg;
            d = d > 1.f ? d : 1.f;
            float inv = 1.f / d;
            float v0 = m0 * inv + bflo(cu) + bv.x;
            float v1 = m1 * inv + bfhi(cu) + bv.y;
            v0 = v0 > 0.f ? v0 : 0.f;
            v1 = v1 > 0.f ? v1 : 0.f;
            unsigned pv = (unsigned)f2bf(v0) | ((unsigned)f2bf(v1) << 16);
            *(unsigned*)&H[(size_t)r * 64 + (c << 1)] = pv;
        }
    }
}

// ---------------- layer-2 GEMM + output GEMM ----------------

__global__ __launch_bounds__(512)
void dual_gemm_b16in(const unsigned short* __restrict__ X, const short* __restrict__ PH,
                     const short* __restrict__ PL, unsigned short* __restrict__ Yl,
                     unsigned short* __restrict__ Yr, int n)
{
    constexpr int NKT = 2;
    __shared__ unsigned short sT[8][16 * 72];
    const int lane = threadIdx.x & 63;
    const int wid  = threadIdx.x >> 6;
    const long ntile = ((long)n + 15) >> 4;
    long t = (long)blockIdx.x * 8 + wid;
    if (t >= ntile) return;
    const long rbase = t << 4;
    long arow = rbase + (lane & 15);
    if (arow >= n) arow = n - 1;
    const int koff = (lane >> 4) << 3;
    const unsigned short* xr = X + arow * 64 + koff;

    s16x8 Bv[NKT];
    #pragma unroll
    for (int kt = 0; kt < NKT; ++kt) Bv[kt] = *(const s16x8*)(xr + kt * 32);

    f32x4 acc[2][4];
    #pragma unroll
    for (int m = 0; m < 2; ++m)
        #pragma unroll
        for (int ct = 0; ct < 4; ++ct) acc[m][ct] = (f32x4)(0.f);

    #pragma unroll
    for (int m = 0; m < 2; ++m)
    #pragma unroll
    for (int ct = 0; ct < 4; ++ct)
    #pragma unroll
    for (int kt = 0; kt < NKT; ++kt) {
        const int fidx = ((((m << 2) | ct) * NKT) + kt) * 64 + lane;
        s16x8 Ah = *(const s16x8*)(PH + (size_t)fidx * 8);
        s16x8 Al = *(const s16x8*)(PL + (size_t)fidx * 8);
        acc[m][ct] = __builtin_amdgcn_mfma_f32_16x16x32_bf16(Ah, Bv[kt], acc[m][ct], 0, 0, 0);
        acc[m][ct] = __builtin_amdgcn_mfma_f32_16x16x32_bf16(Al, Bv[kt], acc[m][ct], 0, 0, 0);
    }

    const int wrow = lane & 15, q4 = (lane >> 4) << 2;
    #pragma unroll
    for (int m = 0; m < 2; ++m) {
        unsigned short* __restrict__ Y = m ? Yr : Yl;
        #pragma unroll
        for (int ct = 0; ct < 4; ++ct) {
            s16x4 pv;
            #pragma unroll
            for (int j = 0; j < 4; ++j) pv[j] = (short)f2bf(acc[m][ct][j]);
            *(s16x4*)&sT[wid][wrow * 72 + ct * 16 + q4] = pv;
        }
        asm volatile("s_waitcnt lgkmcnt(0)" ::: "memory");
        if (rbase + 16 <= (long)n) {
            #pragma unroll
            for (int s = 0; s < 2; ++s) {
                int f = s * 64 + lane;
                s16x8 v = *(const s16x8*)&sT[wid][(f >> 3) * 72 + ((f & 7) << 3)];
                *(s16x8*)&Y[rbase * 64 + (size_t)f * 8] = v;
            }
        } else {
            #pragma unroll
            for (int s = 0; s < 2; ++s) {
                int f = s * 64 + lane;
                s16x8 v = *(const s16x8*)&sT[wid][(f >> 3) * 72 + ((f & 7) << 3)];
                long g = rbase * 64 + (size_t)f * 8;
                #pragma unroll
                for (int jj = 0; jj < 8; ++jj)
                    if (g + jj < (long)n * 64) Y[g + jj] = (unsigned short)v[jj];
            }
        }
        asm volatile("s_waitcnt lgkmcnt(0)" ::: "memory");
    }
}

__global__ __launch_bounds__(512)
void gemm_out_mfma(const unsigned short* __restrict__ X, const short* __restrict__ PH,
                   const short* __restrict__ PL, const float* __restrict__ bo,
                   float* __restrict__ Y, int n)
{
    constexpr int NCT = 7;
    __shared__ float sT[8][16 * 120];
    const int lane = threadIdx.x & 63;
    const int wid  = threadIdx.x >> 6;
    const long ntile = ((long)n + 15) >> 4;
    long t = (long)blockIdx.x * 8 + wid;
    if (t >= ntile) return;
    const long rbase = t << 4;
    long arow = rbase + (lane & 15);
    if (arow >= n) arow = n - 1;
    const int koff = (lane >> 4) << 3;
    const unsigned short* xr = X + arow * 64 + koff;

    s16x8 Bv[2];
    #pragma unroll
    for (int kt = 0; kt < 2; ++kt) Bv[kt] = *(const s16x8*)(xr + kt * 32);

    f32x4 acc[NCT];
    #pragma unroll
    for (int ct = 0; ct < NCT; ++ct) acc[ct] = (f32x4)(0.f);

    #pragma unroll
    for (int ct = 0; ct < NCT; ++ct)
    #pragma unroll
    for (int kt = 0; kt < 2; ++kt) {
        const int fidx = (ct * 2 + kt) * 64 + lane;
        s16x8 Ah = *(const s16x8*)(PH + (size_t)fidx * 8);
        s16x8 Al = *(const s16x8*)(PL + (size_t)fidx * 8);
        acc[ct] = __builtin_amdgcn_mfma_f32_16x16x32_bf16(Ah, Bv[kt], acc[ct], 0, 0, 0);
        acc[ct] = __builtin_amdgcn_mfma_f32_16x16x32_bf16(Al, Bv[kt], acc[ct], 0, 0, 0);
    }

    const int wrow = lane & 15, q4 = (lane >> 4) << 2;
    #pragma unroll
    for (int ct = 0; ct < NCT; ++ct)
        *(f32x4*)&sT[wid][wrow * 120 + ct * 16 + q4] = acc[ct];
    asm volatile("s_waitcnt lgkmcnt(0)" ::: "memory");

    if (rbase + 16 <= (long)n) {
        #pragma unroll
        for (int s = 0; s < 7; ++s) {
            int f = s * 64 + lane;
            int row = f / 28, ch = f % 28;
            f32x4 v = *(const f32x4*)&sT[wid][row * 120 + ch * 4];
            f32x4 b4 = *(const f32x4*)&bo[ch * 4];
            v.x += b4.x; v.y += b4.y; v.z += b4.z; v.w += b4.w;
            *(f32x4*)&Y[rbase * 112 + (size_t)f * 4] = v;
        }
    } else {
        #pragma unroll
        for (int s = 0; s < 7; ++s) {
            int f = s * 64 + lane;
            int row = f / 28, ch = f % 28;
            f32x4 v = *(const f32x4*)&sT[wid][row * 120 + ch * 4];
            #pragma unroll
            for (int jj = 0; jj < 4; ++jj) {
                long g = rbase * 112 + (size_t)f * 4 + jj;
                if (g < (long)n * 112) Y[g] = v[jj] + bo[ch * 4 + jj];
            }
        }
    }
}

// ---------------- launch ----------------

extern "C" void kernel_launch(void* const* d_in, const int* in_sizes, int n_in,
                              void* d_out, int out_size, void* d_ws, size_t ws_size,
                              hipStream_t stream)
{
    const float* x   = (const float*)d_in[0];
    const int*   ei  = (const int*)d_in[1];
    const float* W1l = (const float*)d_in[2];
    const float* b1  = (const float*)d_in[3];
    const float* W1r = (const float*)d_in[4];
    const float* W2l = (const float*)d_in[5];
    const float* b2  = (const float*)d_in[6];
    const float* W2r = (const float*)d_in[7];
    const float* Wo  = (const float*)d_in[8];
    const float* bo  = (const float*)d_in[9];
    float* out = (float*)d_out;

    const int n = in_sizes[0] / 128;
    const int E = in_sizes[1] / 2;
    const int* srcI = ei;
    const int* dstI = ei + E;
    const int nbkt   = (n + 511) >> 9;
    const size_t nn64 = (size_t)n * 64;
    const size_t csrCap = (size_t)E + (size_t)8 * n + 16;   // pad-8 capacity

    unsigned short* A = (unsigned short*)d_ws;    // (n+1)*64 bf16 (row n = dummy)
    unsigned short* C = A + nn64 + 64;            // n*64
    unsigned short* H = C + nn64;                 // n*64
    int*   rowptrP= (int*)(H + nn64);             // n+1
    int*   degi   = rowptrP + n + 1;              // n
    int*   partial= degi + n;                     // 260
    int*   csr    = partial + 260;                // csrCap (byte offsets)
    int*   packed = csr + csrCap;                 // nbkt * BSTRIDE
    int*   gcursor= packed + (size_t)nbkt * BSTRIDE;  // nbkt (per-bucket counts)
    short* PH1    = (short*)(gcursor + nbkt);     // 16384
    short* PL1    = PH1 + 16384;
    short* PH2    = PL1 + 16384;                  // 8192
    short* PL2    = PH2 + 8192;
    short* PHo    = PL2 + 8192;                   // 7168
    short* PLo    = PHo + 7168;

    const long ntile = ((long)n + 15) >> 4;
    const int gmf = (int)((ntile + 7) / 8);
    const int sctBlocks = (int)((E + 2047) / 2048);

    // ---- prep (gcursor zeroed inside pack_frags) ----
    pack_frags<<<16, 256, 0, stream>>>(W1l, W1r, W2l, W2r, Wo,
                                       PH1, PL1, PH2, PL2, PHo, PLo, gcursor, nbkt);

    // ---- GEMM1 (first in grid) overlapped with scatter (fixed-stride buckets) ----
    fused_gemm1_scatter<<<gmf + sctBlocks, 512, 0, stream>>>(
        x, PH1, PL1, A, C, n, srcI, dstI, gcursor, packed, E, nbkt, gmf);

    // ---- CSR build: hist+scan -> fill+finalize (prefix computed in-kernel) ----
    hist_scan<<<nbkt, 256, 0, stream>>>(packed, gcursor, degi, rowptrP, partial, n);
    bucket_fill_final<<<nbkt, 256, 0, stream>>>(packed, gcursor, partial, rowptrP,
                                                csr, (unsigned*)(A + nn64), n, nbkt, n << 7);

    // ---- layer 1 aggregation ----
    pull_agg_pad<<<4096, 256, 0, stream>>>(A, rowptrP, degi, csr, C, b1, H, n);

    // ---- layer 2 ----
    dual_gemm_b16in<<<gmf, 512, 0, stream>>>(H, PH2, PL2, A, C, n);
    pull_agg_pad<<<4096, 256, 0, stream>>>(A, rowptrP, degi, csr, C, b2, H, n);

    // ---- output projection ----
    gemm_out_mfma<<<gmf, 512, 0, stream>>>(H, PHo, PLo, bo, out, n);
}

// Round 17
// 179.861 us; speedup vs baseline: 1.0498x; 1.0498x over previous
//
#include <hip/hip_runtime.h>

typedef float f32x4 __attribute__((ext_vector_type(4)));
typedef short s16x8 __attribute__((ext_vector_type(8)));
typedef short s16x4 __attribute__((ext_vector_type(4)));

#define BSTRIDE 9216   // fixed per-bucket capacity in packed[]; E*512/n=8192 expected, +11 sigma

__device__ __forceinline__ unsigned short f2bf(float f) {
    unsigned u = __builtin_bit_cast(unsigned, f);
    unsigned r = (u + 0x7FFFu + ((u >> 16) & 1u)) >> 16;
    return (unsigned short)r;
}
__device__ __forceinline__ float bf2f(unsigned short h) {
    unsigned u = ((unsigned)h) << 16;
    return __builtin_bit_cast(float, u);
}
__device__ __forceinline__ float bflo(unsigned u) {
    return __builtin_bit_cast(float, u << 16);
}
__device__ __forceinline__ float bfhi(unsigned u) {
    return __builtin_bit_cast(float, u & 0xffff0000u);
}

// ---------------- weight fragment packing (+ gcursor zero) ----------------
__global__ __launch_bounds__(256)
void pack_frags(const float* __restrict__ W1l, const float* __restrict__ W1r,
                const float* __restrict__ W2l, const float* __restrict__ W2r,
                const float* __restrict__ Wo,
                short* __restrict__ PH1, short* __restrict__ PL1,
                short* __restrict__ PH2, short* __restrict__ PL2,
                short* __restrict__ PHo, short* __restrict__ PLo,
                int* __restrict__ gcursor, int nbkt)
{
    if (blockIdx.x == 0)
        for (int i = threadIdx.x; i < nbkt; i += 256) gcursor[i] = 0;
    const int tot = 2048 + 1024 + 896;
    for (int e = blockIdx.x * 256 + threadIdx.x; e < tot; e += gridDim.x * 256) {
        int lane, f, k0, c, stride;
        const float* W;
        short *PH, *PL;
        int idx;
        if (e < 2048) {
            idx = e; lane = e & 63; f = e >> 6;
            int kt = f & 3, ct = (f >> 2) & 3, m = f >> 4;
            W = m ? W1r : W1l; PH = PH1; PL = PL1;
            k0 = kt * 32 + ((lane >> 4) << 3);
            c  = ct * 16 + (lane & 15);
            stride = 64;
        } else if (e < 3072) {
            int e2 = e - 2048;
            idx = e2; lane = e2 & 63; f = e2 >> 6;
            int kt = f & 1, ct = (f >> 1) & 3, m = f >> 3;
            W = m ? W2r : W2l; PH = PH2; PL = PL2;
            k0 = kt * 32 + ((lane >> 4) << 3);
            c  = ct * 16 + (lane & 15);
            stride = 64;
        } else {
            int eo = e - 3072;
            idx = eo; lane = eo & 63; f = eo >> 6;
            int kt = f & 1, ct = f >> 1;
            W = Wo; PH = PHo; PL = PLo;
            k0 = kt * 32 + ((lane >> 4) << 3);
            c  = ct * 16 + (lane & 15);
            stride = 112;
        }
        short h[8], l[8];
        #pragma unroll
        for (int j = 0; j < 8; ++j) {
            float v = W[(size_t)(k0 + j) * stride + c];
            unsigned short hb = f2bf(v);
            h[j] = (short)hb;
            l[j] = (short)f2bf(v - bf2f(hb));
        }
        #pragma unroll
        for (int j = 0; j < 8; ++j) { PH[idx * 8 + j] = h[j]; PL[idx * 8 + j] = l[j]; }
    }
}

// ------- fused: bucket_scatter (blocks [0,sctBlocks)) + GEMM1 (rest) -------
// Scatter: 8192 edges/block (16/thread) into fixed-stride bucket segments.
// GEMM1 = x @ {W1l,W1r}, f32 in (3-term hi/lo), bf16 out.
__global__ __launch_bounds__(512)
void fused_gemm1_scatter(const float* __restrict__ X, const short* __restrict__ PH,
                         const short* __restrict__ PL, unsigned short* __restrict__ Yl,
                         unsigned short* __restrict__ Yr, int n,
                         const int* __restrict__ src, const int* __restrict__ dst,
                         int* __restrict__ gcursor, int* __restrict__ packed,
                         int E, int B, int sctBlocks)
{
    __shared__ unsigned short sT[8][16 * 72];
    __shared__ int lh[256];
    __shared__ int lbase[256];

    if ((int)blockIdx.x < sctBlocks) {
        // ---- bucket scatter (8192 edges/block, 16/thread) ----
        for (int i = threadIdx.x; i < B; i += 512) lh[i] = 0;
        __syncthreads();
        long base = (long)blockIdx.x * 8192;
        int bkt[16], rnk[16], pk[16];
        #pragma unroll
        for (int j = 0; j < 16; ++j) {
            long e = base + j * 512 + threadIdx.x;
            if (e < E) {
                int d = dst[e], s = src[e];
                bkt[j] = d >> 9;
                pk[j]  = (s << 9) | (d & 511);
                rnk[j] = atomicAdd(&lh[bkt[j]], 1);
            } else bkt[j] = -1;
        }
        __syncthreads();
        for (int i = threadIdx.x; i < B; i += 512) {
            int v = lh[i];
            lbase[i] = v ? atomicAdd(&gcursor[i], v) : 0;
        }
        __syncthreads();
        #pragma unroll
        for (int j = 0; j < 16; ++j)
            if (bkt[j] >= 0)
                packed[(size_t)bkt[j] * BSTRIDE + lbase[bkt[j]] + rnk[j]] = pk[j];
        return;
    }

    // ---- GEMM1 ----
    constexpr int K = 128, NKT = 4;
    const int lane = threadIdx.x & 63;
    const int wid  = threadIdx.x >> 6;
    const long ntile = ((long)n + 15) >> 4;
    long t = (long)(blockIdx.x - sctBlocks) * 8 + wid;
    if (t >= ntile) return;
    const long rbase = t << 4;
    long arow = rbase + (lane & 15);
    if (arow >= n) arow = n - 1;
    const int koff = (lane >> 4) << 3;
    const float* xr = X + arow * K + koff;

    s16x8 Bh[NKT], Bl[NKT];
    #pragma unroll
    for (int kt = 0; kt < NKT; ++kt) {
        f32x4 a0 = *(const f32x4*)(xr + kt * 32);
        f32x4 a1 = *(const f32x4*)(xr + kt * 32 + 4);
        s16x8 h, l;
        #pragma unroll
        for (int j = 0; j < 4; ++j) {
            float v = a0[j]; unsigned short hb = f2bf(v);
            h[j] = (short)hb; l[j] = (short)f2bf(v - bf2f(hb));
            float v2 = a1[j]; unsigned short hb2 = f2bf(v2);
            h[4 + j] = (short)hb2; l[4 + j] = (short)f2bf(v2 - bf2f(hb2));
        }
        Bh[kt] = h; Bl[kt] = l;
    }

    f32x4 acc[2][4];
    #pragma unroll
    for (int m = 0; m < 2; ++m)
        #pragma unroll
        for (int ct = 0; ct < 4; ++ct) acc[m][ct] = (f32x4)(0.f);

    #pragma unroll
    for (int m = 0; m < 2; ++m)
    #pragma unroll
    for (int ct = 0; ct < 4; ++ct)
    #pragma unroll
    for (int kt = 0; kt < NKT; ++kt) {
        const int fidx = ((((m << 2) | ct) * NKT) + kt) * 64 + lane;
        s16x8 Ah = *(const s16x8*)(PH + (size_t)fidx * 8);
        s16x8 Al = *(const s16x8*)(PL + (size_t)fidx * 8);
        acc[m][ct] = __builtin_amdgcn_mfma_f32_16x16x32_bf16(Ah, Bh[kt], acc[m][ct], 0, 0, 0);
        acc[m][ct] = __builtin_amdgcn_mfma_f32_16x16x32_bf16(Al, Bh[kt], acc[m][ct], 0, 0, 0);
        acc[m][ct] = __builtin_amdgcn_mfma_f32_16x16x32_bf16(Ah, Bl[kt], acc[m][ct], 0, 0, 0);
    }

    const int wrow = lane & 15, q4 = (lane >> 4) << 2;
    #pragma unroll
    for (int m = 0; m < 2; ++m) {
        unsigned short* __restrict__ Y = m ? Yr : Yl;
        #pragma unroll
        for (int ct = 0; ct < 4; ++ct) {
            s16x4 pv;
            #pragma unroll
            for (int j = 0; j < 4; ++j) pv[j] = (short)f2bf(acc[m][ct][j]);
            *(s16x4*)&sT[wid][wrow * 72 + ct * 16 + q4] = pv;
        }
        asm volatile("s_waitcnt lgkmcnt(0)" ::: "memory");
        if (rbase + 16 <= (long)n) {
            #pragma unroll
            for (int s = 0; s < 2; ++s) {
                int f = s * 64 + lane;
                s16x8 v = *(const s16x8*)&sT[wid][(f >> 3) * 72 + ((f & 7) << 3)];
                *(s16x8*)&Y[rbase * 64 + (size_t)f * 8] = v;
            }
        } else {
            #pragma unroll
            for (int s = 0; s < 2; ++s) {
                int f = s * 64 + lane;
                s16x8 v = *(const s16x8*)&sT[wid][(f >> 3) * 72 + ((f & 7) << 3)];
                long g = rbase * 64 + (size_t)f * 8;
                #pragma unroll
                for (int jj = 0; jj < 8; ++jj)
                    if (g + jj < (long)n * 64) Y[g + jj] = (unsigned short)v[jj];
            }
        }
        asm volatile("s_waitcnt lgkmcnt(0)" ::: "memory");
    }
}

// per bucket: histogram + in-LDS exclusive scan of PAD8 degrees.
__global__ __launch_bounds__(256)
void hist_scan(const int* __restrict__ packed, const int* __restrict__ cnts,
               int* __restrict__ degi, int* __restrict__ rowptrP,
               int* __restrict__ partial, int n)
{
    __shared__ int h[512];
    __shared__ int s[256];
    const int b = blockIdx.x, t = threadIdx.x, nb = b << 9;
    int cnt = n - nb; if (cnt > 512) cnt = 512;
    for (int i = t; i < 512; i += 256) h[i] = 0;
    __syncthreads();
    int bs = b * BSTRIDE, be = bs + cnts[b];
    for (int i = bs + t; i < be; i += 256)
        atomicAdd(&h[packed[i] & 511], 1);
    __syncthreads();
    int e0 = (2 * t     < cnt) ? h[2 * t]     : 0;
    int e1 = (2 * t + 1 < cnt) ? h[2 * t + 1] : 0;
    int p0 = (e0 + 7) & ~7;
    int p1 = (e1 + 7) & ~7;
    int mysum = p0 + p1;
    s[t] = mysum;
    __syncthreads();
    for (int off = 1; off < 256; off <<= 1) {
        int u = (t >= off) ? s[t - off] : 0;
        __syncthreads();
        s[t] += u;
        __syncthreads();
    }
    int excl = s[t] - mysum;
    if (2 * t < cnt)     { degi[nb + 2 * t]     = e0; rowptrP[nb + 2 * t]     = excl; }
    if (2 * t + 1 < cnt) { degi[nb + 2 * t + 1] = e1; rowptrP[nb + 2 * t + 1] = excl + p0; }
    if (t == 255) partial[b] = s[255];
}

// fill + finalize: compute bucket prefix (cooperative sum of partial[0..b)),
// add to rowptrP (write back global), fill csr (byte offsets), dummy-pad,
// write rowptrP[n] (last block), zero dummy feat row (block 0).
__global__ __launch_bounds__(256)
void bucket_fill_final(const int* __restrict__ packed, const int* __restrict__ cnts,
                       const int* __restrict__ partial, int* __restrict__ rowptrP,
                       int* __restrict__ csr, unsigned* __restrict__ Adummy,
                       int n, int nbkt, int dummyOff)
{
    __shared__ int cur[512];
    __shared__ int rs[513];
    __shared__ int red[256];
    const int b = blockIdx.x, t = threadIdx.x, nb = b << 9;
    int cnt = n - nb; if (cnt > 512) cnt = 512;

    // cooperative sum of partial[0..b)
    int loc = 0;
    for (int j = t; j < b; j += 256) loc += partial[j];
    red[t] = loc;
    __syncthreads();
    for (int off = 128; off > 0; off >>= 1) {
        if (t < off) red[t] += red[t + off];
        __syncthreads();
    }
    const int base = red[0];
    const int bend = base + partial[b];

    for (int i = t; i < cnt; i += 256) {
        int v = rowptrP[nb + i] + base;
        rowptrP[nb + i] = v;
        cur[i] = v;
        rs[i] = v;
    }
    if (t == 0) rs[cnt] = bend;
    if (b == nbkt - 1 && t == 0) rowptrP[n] = bend;
    if (b == 0 && t < 32) Adummy[t] = 0u;
    __syncthreads();

    int bs = b * BSTRIDE, be = bs + cnts[b];
    for (int i = bs + t; i < be; i += 256) {
        int p = packed[i];
        int pos = atomicAdd(&cur[p & 511], 1);
        csr[pos] = (p >> 9) << 7;
    }
    __syncthreads();
    for (int i = t; i < cnt; i += 256) {
        int end = rs[i + 1];
        for (int p = cur[i]; p < end; ++p) csr[p] = dummyOff;
    }
}

// ---- pull + fused epilogue, PAD-8 lists, pipelined offsets, 2 rows/wave ----
__global__ __launch_bounds__(256)
void pull_agg_pad(const unsigned short* __restrict__ feat, const int* __restrict__ rowptrP,
                  const int* __restrict__ degi, const int* __restrict__ csrB,
                  const unsigned short* __restrict__ C, const float* __restrict__ bias,
                  unsigned short* __restrict__ H, int n)
{
    const int lane = threadIdx.x & 63;
    const int half = lane >> 5;
    const int c    = lane & 31;
    const int wid  = threadIdx.x >> 6;
    const char* fb = (const char*)feat;
    const int cb   = c << 2;
    const float2 bv = *(const float2*)&bias[c * 2];

    const long w  = (long)blockIdx.x * 4 + wid;
    const long nw = (long)gridDim.x * 4;
    for (long rp = w * 2; rp < n; rp += nw * 2) {
        int2 rr = *(const int2*)&rowptrP[rp];
        int eB = (rp + 1 < n) ? rowptrP[rp + 2] : rr.y;

        const long r = rp + half;
        int dg = 1; unsigned cu = 0;
        if (r < n) {
            dg = degi[r];
            cu = *(const unsigned*)&C[(size_t)r * 64 + (c << 1)];
        }

        int iA = rr.x + (half << 2);
        int iB = rr.y + (half << 2);
        const int endA = rr.y, endB = eB;
        bool dA = iA < endA, dB = iB < endB;
        int4 oA = (int4)(0), oB = (int4)(0);
        if (dA) oA = *(const int4*)&csrB[iA];
        if (dB) oB = *(const int4*)&csrB[iB];

        float a0A = 0.f, a1A = 0.f, a0B = 0.f, a1B = 0.f;
        while (dA | dB) {
            unsigned uA0, uA1, uA2, uA3, uB0, uB1, uB2, uB3;
            if (dA) {
                uA0 = *(const unsigned*)(fb + oA.x + cb);
                uA1 = *(const unsigned*)(fb + oA.y + cb);
                uA2 = *(const unsigned*)(fb + oA.z + cb);
                uA3 = *(const unsigned*)(fb + oA.w + cb);
            }
            if (dB) {
                uB0 = *(const unsigned*)(fb + oB.x + cb);
                uB1 = *(const unsigned*)(fb + oB.y + cb);
                uB2 = *(const unsigned*)(fb + oB.z + cb);
                uB3 = *(const unsigned*)(fb + oB.w + cb);
            }
            int niA = iA + 8, niB = iB + 8;
            bool ndA = niA < endA, ndB = niB < endB;
            int4 tA = oA, tB = oB;
            if (ndA) tA = *(const int4*)&csrB[niA];
            if (ndB) tB = *(const int4*)&csrB[niB];
            if (dA) {
                a0A += bflo(uA0); a1A += bfhi(uA0);
                a0A += bflo(uA1); a1A += bfhi(uA1);
                a0A += bflo(uA2); a1A += bfhi(uA2);
                a0A += bflo(uA3); a1A += bfhi(uA3);
            }
            if (dB) {
                a0B += bflo(uB0); a1B += bfhi(uB0);
                a0B += bflo(uB1); a1B += bfhi(uB1);
                a0B += bflo(uB2); a1B += bfhi(uB2);
                a0B += bflo(uB3); a1B += bfhi(uB3);
            }
            oA = tA; oB = tB; iA = niA; iB = niB; dA = ndA; dB = ndB;
        }

        a0A += __shfl_xor(a0A, 32, 64);
        a1A += __shfl_xor(a1A, 32, 64);
        a0B += __shfl_xor(a0B, 32, 64);
        a1B += __shfl_xor(a1B, 32, 64);

        if (r < n) {
            float m0 = half ? a0B : a0A;
            float m1 = half ? a1B : a1A;
            float d = (float)dg;
            d = d > 1.f ? d : 1.f;
            float inv = 1.f / d;
            float v0 = m0 * inv + bflo(cu) + bv.x;
            float v1 = m1 * inv + bfhi(cu) + bv.y;
            v0 = v0 > 0.f ? v0 : 0.f;
            v1 = v1 > 0.f ? v1 : 0.f;
            unsigned pv = (unsigned)f2bf(v0) | ((unsigned)f2bf(v1) << 16);
            *(unsigned*)&H[(size_t)r * 64 + (c << 1)] = pv;
        }
    }
}

// ---------------- layer-2 GEMM + output GEMM ----------------

__global__ __launch_bounds__(512)
void dual_gemm_b16in(const unsigned short* __restrict__ X, const short* __restrict__ PH,
                     const short* __restrict__ PL, unsigned short* __restrict__ Yl,
                     unsigned short* __restrict__ Yr, int n)
{
    constexpr int NKT = 2;
    __shared__ unsigned short sT[8][16 * 72];
    const int lane = threadIdx.x & 63;
    const int wid  = threadIdx.x >> 6;
    const long ntile = ((long)n + 15) >> 4;
    long t = (long)blockIdx.x * 8 + wid;
    if (t >= ntile) return;
    const long rbase = t << 4;
    long arow = rbase + (lane & 15);
    if (arow >= n) arow = n - 1;
    const int koff = (lane >> 4) << 3;
    const unsigned short* xr = X + arow * 64 + koff;

    s16x8 Bv[NKT];
    #pragma unroll
    for (int kt = 0; kt < NKT; ++kt) Bv[kt] = *(const s16x8*)(xr + kt * 32);

    f32x4 acc[2][4];
    #pragma unroll
    for (int m = 0; m < 2; ++m)
        #pragma unroll
        for (int ct = 0; ct < 4; ++ct) acc[m][ct] = (f32x4)(0.f);

    #pragma unroll
    for (int m = 0; m < 2; ++m)
    #pragma unroll
    for (int ct = 0; ct < 4; ++ct)
    #pragma unroll
    for (int kt = 0; kt < NKT; ++kt) {
        const int fidx = ((((m << 2) | ct) * NKT) + kt) * 64 + lane;
        s16x8 Ah = *(const s16x8*)(PH + (size_t)fidx * 8);
        s16x8 Al = *(const s16x8*)(PL + (size_t)fidx * 8);
        acc[m][ct] = __builtin_amdgcn_mfma_f32_16x16x32_bf16(Ah, Bv[kt], acc[m][ct], 0, 0, 0);
        acc[m][ct] = __builtin_amdgcn_mfma_f32_16x16x32_bf16(Al, Bv[kt], acc[m][ct], 0, 0, 0);
    }

    const int wrow = lane & 15, q4 = (lane >> 4) << 2;
    #pragma unroll
    for (int m = 0; m < 2; ++m) {
        unsigned short* __restrict__ Y = m ? Yr : Yl;
        #pragma unroll
        for (int ct = 0; ct < 4; ++ct) {
            s16x4 pv;
            #pragma unroll
            for (int j = 0; j < 4; ++j) pv[j] = (short)f2bf(acc[m][ct][j]);
            *(s16x4*)&sT[wid][wrow * 72 + ct * 16 + q4] = pv;
        }
        asm volatile("s_waitcnt lgkmcnt(0)" ::: "memory");
        if (rbase + 16 <= (long)n) {
            #pragma unroll
            for (int s = 0; s < 2; ++s) {
                int f = s * 64 + lane;
                s16x8 v = *(const s16x8*)&sT[wid][(f >> 3) * 72 + ((f & 7) << 3)];
                *(s16x8*)&Y[rbase * 64 + (size_t)f * 8] = v;
            }
        } else {
            #pragma unroll
            for (int s = 0; s < 2; ++s) {
                int f = s * 64 + lane;
                s16x8 v = *(const s16x8*)&sT[wid][(f >> 3) * 72 + ((f & 7) << 3)];
                long g = rbase * 64 + (size_t)f * 8;
                #pragma unroll
                for (int jj = 0; jj < 8; ++jj)
                    if (g + jj < (long)n * 64) Y[g + jj] = (unsigned short)v[jj];
            }
        }
        asm volatile("s_waitcnt lgkmcnt(0)" ::: "memory");
    }
}

__global__ __launch_bounds__(512)
void gemm_out_mfma(const unsigned short* __restrict__ X, const short* __restrict__ PH,
                   const short* __restrict__ PL, const float* __restrict__ bo,
                   float* __restrict__ Y, int n)
{
    constexpr int NCT = 7;
    __shared__ float sT[8][16 * 120];
    const int lane = threadIdx.x & 63;
    const int wid  = threadIdx.x >> 6;
    const long ntile = ((long)n + 15) >> 4;
    long t = (long)blockIdx.x * 8 + wid;
    if (t >= ntile) return;
    const long rbase = t << 4;
    long arow = rbase + (lane & 15);
    if (arow >= n) arow = n - 1;
    const int koff = (lane >> 4) << 3;
    const unsigned short* xr = X + arow * 64 + koff;

    s16x8 Bv[2];
    #pragma unroll
    for (int kt = 0; kt < 2; ++kt) Bv[kt] = *(const s16x8*)(xr + kt * 32);

    f32x4 acc[NCT];
    #pragma unroll
    for (int ct = 0; ct < NCT; ++ct) acc[ct] = (f32x4)(0.f);

    #pragma unroll
    for (int ct = 0; ct < NCT; ++ct)
    #pragma unroll
    for (int kt = 0; kt < 2; ++kt) {
        const int fidx = (ct * 2 + kt) * 64 + lane;
        s16x8 Ah = *(const s16x8*)(PH + (size_t)fidx * 8);
        s16x8 Al = *(const s16x8*)(PL + (size_t)fidx * 8);
        acc[ct] = __builtin_amdgcn_mfma_f32_16x16x32_bf16(Ah, Bv[kt], acc[ct], 0, 0, 0);
        acc[ct] = __builtin_amdgcn_mfma_f32_16x16x32_bf16(Al, Bv[kt], acc[ct], 0, 0, 0);
    }

    const int wrow = lane & 15, q4 = (lane >> 4) << 2;
    #pragma unroll
    for (int ct = 0; ct < NCT; ++ct)
        *(f32x4*)&sT[wid][wrow * 120 + ct * 16 + q4] = acc[ct];
    asm volatile("s_waitcnt lgkmcnt(0)" ::: "memory");

    if (rbase + 16 <= (long)n) {
        #pragma unroll
        for (int s = 0; s < 7; ++s) {
            int f = s * 64 + lane;
            int row = f / 28, ch = f % 28;
            f32x4 v = *(const f32x4*)&sT[wid][row * 120 + ch * 4];
            f32x4 b4 = *(const f32x4*)&bo[ch * 4];
            v.x += b4.x; v.y += b4.y; v.z += b4.z; v.w += b4.w;
            *(f32x4*)&Y[rbase * 112 + (size_t)f * 4] = v;
        }
    } else {
        #pragma unroll
        for (int s = 0; s < 7; ++s) {
            int f = s * 64 + lane;
            int row = f / 28, ch = f % 28;
            f32x4 v = *(const f32x4*)&sT[wid][row * 120 + ch * 4];
            #pragma unroll
            for (int jj = 0; jj < 4; ++jj) {
                long g = rbase * 112 + (size_t)f * 4 + jj;
                if (g < (long)n * 112) Y[g] = v[jj] + bo[ch * 4 + jj];
            }
        }
    }
}

// ---------------- launch ----------------

extern "C" void kernel_launch(void* const* d_in, const int* in_sizes, int n_in,
                              void* d_out, int out_size, void* d_ws, size_t ws_size,
                              hipStream_t stream)
{
    const float* x   = (const float*)d_in[0];
    const int*   ei  = (const int*)d_in[1];
    const float* W1l = (const float*)d_in[2];
    const float* b1  = (const float*)d_in[3];
    const float* W1r = (const float*)d_in[4];
    const float* W2l = (const float*)d_in[5];
    const float* b2  = (const float*)d_in[6];
    const float* W2r = (const float*)d_in[7];
    const float* Wo  = (const float*)d_in[8];
    const float* bo  = (const float*)d_in[9];
    float* out = (float*)d_out;

    const int n = in_sizes[0] / 128;
    const int E = in_sizes[1] / 2;
    const int* srcI = ei;
    const int* dstI = ei + E;
    const int nbkt   = (n + 511) >> 9;
    const size_t nn64 = (size_t)n * 64;
    const size_t csrCap = (size_t)E + (size_t)8 * n + 16;   // pad-8 capacity

    unsigned short* A = (unsigned short*)d_ws;    // (n+1)*64 bf16 (row n = dummy)
    unsigned short* C = A + nn64 + 64;            // n*64
    unsigned short* H = C + nn64;                 // n*64
    int*   rowptrP= (int*)(H + nn64);             // n+1
    int*   degi   = rowptrP + n + 1;              // n
    int*   partial= degi + n;                     // 260
    int*   csr    = partial + 260;                // csrCap (byte offsets)
    int*   packed = csr + csrCap;                 // nbkt * BSTRIDE
    int*   gcursor= packed + (size_t)nbkt * BSTRIDE;  // nbkt (per-bucket counts)
    short* PH1    = (short*)(gcursor + nbkt);     // 16384
    short* PL1    = PH1 + 16384;
    short* PH2    = PL1 + 16384;                  // 8192
    short* PL2    = PH2 + 8192;
    short* PHo    = PL2 + 8192;                   // 7168
    short* PLo    = PHo + 7168;

    const long ntile = ((long)n + 15) >> 4;
    const int gmf = (int)((ntile + 7) / 8);
    const int sctBlocks = (int)((E + 8191) / 8192);

    // ---- prep (gcursor zeroed inside pack_frags) ----
    pack_frags<<<16, 256, 0, stream>>>(W1l, W1r, W2l, W2r, Wo,
                                       PH1, PL1, PH2, PL2, PHo, PLo, gcursor, nbkt);

    // ---- scatter (fixed-stride buckets, first in grid) overlapped with GEMM1 ----
    fused_gemm1_scatter<<<sctBlocks + gmf, 512, 0, stream>>>(
        x, PH1, PL1, A, C, n, srcI, dstI, gcursor, packed, E, nbkt, sctBlocks);

    // ---- CSR build: hist+scan -> fill+finalize (prefix computed in-kernel) ----
    hist_scan<<<nbkt, 256, 0, stream>>>(packed, gcursor, degi, rowptrP, partial, n);
    bucket_fill_final<<<nbkt, 256, 0, stream>>>(packed, gcursor, partial, rowptrP,
                                                csr, (unsigned*)(A + nn64), n, nbkt, n << 7);

    // ---- layer 1 aggregation ----
    pull_agg_pad<<<4096, 256, 0, stream>>>(A, rowptrP, degi, csr, C, b1, H, n);

    // ---- layer 2 ----
    dual_gemm_b16in<<<gmf, 512, 0, stream>>>(H, PH2, PL2, A, C, n);
    pull_agg_pad<<<4096, 256, 0, stream>>>(A, rowptrP, degi, csr, C, b2, H, n);

    // ---- output projection ----
    gemm_out_mfma<<<gmf, 512, 0, stream>>>(H, PHo, PLo, bo, out, n);
}

// Round 18
// 171.246 us; speedup vs baseline: 1.1027x; 1.0503x over previous
//
#include <hip/hip_runtime.h>

typedef float f32x4 __attribute__((ext_vector_type(4)));
typedef short s16x8 __attribute__((ext_vector_type(8)));
typedef short s16x4 __attribute__((ext_vector_type(4)));

#define BSTRIDE 9216   // fixed per-bucket capacity in packed[]; E*512/n=8192 expected, +11 sigma

__device__ __forceinline__ unsigned short f2bf(float f) {
    unsigned u = __builtin_bit_cast(unsigned, f);
    unsigned r = (u + 0x7FFFu + ((u >> 16) & 1u)) >> 16;
    return (unsigned short)r;
}
__device__ __forceinline__ float bf2f(unsigned short h) {
    unsigned u = ((unsigned)h) << 16;
    return __builtin_bit_cast(float, u);
}
__device__ __forceinline__ float bflo(unsigned u) {
    return __builtin_bit_cast(float, u << 16);
}
__device__ __forceinline__ float bfhi(unsigned u) {
    return __builtin_bit_cast(float, u & 0xffff0000u);
}

// ---------------- weight fragment packing (+ gcursor zero) ----------------
__global__ __launch_bounds__(256)
void pack_frags(const float* __restrict__ W1l, const float* __restrict__ W1r,
                const float* __restrict__ W2l, const float* __restrict__ W2r,
                const float* __restrict__ Wo,
                short* __restrict__ PH1, short* __restrict__ PL1,
                short* __restrict__ PH2, short* __restrict__ PL2,
                short* __restrict__ PHo, short* __restrict__ PLo,
                int* __restrict__ gcursor, int nbkt)
{
    if (blockIdx.x == 0)
        for (int i = threadIdx.x; i < nbkt; i += 256) gcursor[i] = 0;
    const int tot = 2048 + 1024 + 896;
    for (int e = blockIdx.x * 256 + threadIdx.x; e < tot; e += gridDim.x * 256) {
        int lane, f, k0, c, stride;
        const float* W;
        short *PH, *PL;
        int idx;
        if (e < 2048) {
            idx = e; lane = e & 63; f = e >> 6;
            int kt = f & 3, ct = (f >> 2) & 3, m = f >> 4;
            W = m ? W1r : W1l; PH = PH1; PL = PL1;
            k0 = kt * 32 + ((lane >> 4) << 3);
            c  = ct * 16 + (lane & 15);
            stride = 64;
        } else if (e < 3072) {
            int e2 = e - 2048;
            idx = e2; lane = e2 & 63; f = e2 >> 6;
            int kt = f & 1, ct = (f >> 1) & 3, m = f >> 3;
            W = m ? W2r : W2l; PH = PH2; PL = PL2;
            k0 = kt * 32 + ((lane >> 4) << 3);
            c  = ct * 16 + (lane & 15);
            stride = 64;
        } else {
            int eo = e - 3072;
            idx = eo; lane = eo & 63; f = eo >> 6;
            int kt = f & 1, ct = f >> 1;
            W = Wo; PH = PHo; PL = PLo;
            k0 = kt * 32 + ((lane >> 4) << 3);
            c  = ct * 16 + (lane & 15);
            stride = 112;
        }
        short h[8], l[8];
        #pragma unroll
        for (int j = 0; j < 8; ++j) {
            float v = W[(size_t)(k0 + j) * stride + c];
            unsigned short hb = f2bf(v);
            h[j] = (short)hb;
            l[j] = (short)f2bf(v - bf2f(hb));
        }
        #pragma unroll
        for (int j = 0; j < 8; ++j) { PH[idx * 8 + j] = h[j]; PL[idx * 8 + j] = l[j]; }
    }
}

// ------- fused: bucket_scatter (blocks [0,sctBlocks)) + GEMM1 (rest) -------
__global__ __launch_bounds__(512)
void fused_gemm1_scatter(const float* __restrict__ X, const short* __restrict__ PH,
                         const short* __restrict__ PL, unsigned short* __restrict__ Yl,
                         unsigned short* __restrict__ Yr, int n,
                         const int* __restrict__ src, const int* __restrict__ dst,
                         int* __restrict__ gcursor, int* __restrict__ packed,
                         int E, int B, int sctBlocks)
{
    __shared__ unsigned short sT[8][16 * 72];
    __shared__ int lh[256];
    __shared__ int lbase[256];

    if ((int)blockIdx.x < sctBlocks) {
        for (int i = threadIdx.x; i < B; i += 512) lh[i] = 0;
        __syncthreads();
        long base = (long)blockIdx.x * 8192;
        int bkt[16], rnk[16], pk[16];
        #pragma unroll
        for (int j = 0; j < 16; ++j) {
            long e = base + j * 512 + threadIdx.x;
            if (e < E) {
                int d = dst[e], s = src[e];
                bkt[j] = d >> 9;
                pk[j]  = (s << 9) | (d & 511);
                rnk[j] = atomicAdd(&lh[bkt[j]], 1);
            } else bkt[j] = -1;
        }
        __syncthreads();
        for (int i = threadIdx.x; i < B; i += 512) {
            int v = lh[i];
            lbase[i] = v ? atomicAdd(&gcursor[i], v) : 0;
        }
        __syncthreads();
        #pragma unroll
        for (int j = 0; j < 16; ++j)
            if (bkt[j] >= 0)
                packed[(size_t)bkt[j] * BSTRIDE + lbase[bkt[j]] + rnk[j]] = pk[j];
        return;
    }

    // ---- GEMM1 ----
    constexpr int K = 128, NKT = 4;
    const int lane = threadIdx.x & 63;
    const int wid  = threadIdx.x >> 6;
    const long ntile = ((long)n + 15) >> 4;
    long t = (long)(blockIdx.x - sctBlocks) * 8 + wid;
    if (t >= ntile) return;
    const long rbase = t << 4;
    long arow = rbase + (lane & 15);
    if (arow >= n) arow = n - 1;
    const int koff = (lane >> 4) << 3;
    const float* xr = X + arow * K + koff;

    s16x8 Bh[NKT], Bl[NKT];
    #pragma unroll
    for (int kt = 0; kt < NKT; ++kt) {
        f32x4 a0 = *(const f32x4*)(xr + kt * 32);
        f32x4 a1 = *(const f32x4*)(xr + kt * 32 + 4);
        s16x8 h, l;
        #pragma unroll
        for (int j = 0; j < 4; ++j) {
            float v = a0[j]; unsigned short hb = f2bf(v);
            h[j] = (short)hb; l[j] = (short)f2bf(v - bf2f(hb));
            float v2 = a1[j]; unsigned short hb2 = f2bf(v2);
            h[4 + j] = (short)hb2; l[4 + j] = (short)f2bf(v2 - bf2f(hb2));
        }
        Bh[kt] = h; Bl[kt] = l;
    }

    f32x4 acc[2][4];
    #pragma unroll
    for (int m = 0; m < 2; ++m)
        #pragma unroll
        for (int ct = 0; ct < 4; ++ct) acc[m][ct] = (f32x4)(0.f);

    #pragma unroll
    for (int m = 0; m < 2; ++m)
    #pragma unroll
    for (int ct = 0; ct < 4; ++ct)
    #pragma unroll
    for (int kt = 0; kt < NKT; ++kt) {
        const int fidx = ((((m << 2) | ct) * NKT) + kt) * 64 + lane;
        s16x8 Ah = *(const s16x8*)(PH + (size_t)fidx * 8);
        s16x8 Al = *(const s16x8*)(PL + (size_t)fidx * 8);
        acc[m][ct] = __builtin_amdgcn_mfma_f32_16x16x32_bf16(Ah, Bh[kt], acc[m][ct], 0, 0, 0);
        acc[m][ct] = __builtin_amdgcn_mfma_f32_16x16x32_bf16(Al, Bh[kt], acc[m][ct], 0, 0, 0);
        acc[m][ct] = __builtin_amdgcn_mfma_f32_16x16x32_bf16(Ah, Bl[kt], acc[m][ct], 0, 0, 0);
    }

    const int wrow = lane & 15, q4 = (lane >> 4) << 2;
    #pragma unroll
    for (int m = 0; m < 2; ++m) {
        unsigned short* __restrict__ Y = m ? Yr : Yl;
        #pragma unroll
        for (int ct = 0; ct < 4; ++ct) {
            s16x4 pv;
            #pragma unroll
            for (int j = 0; j < 4; ++j) pv[j] = (short)f2bf(acc[m][ct][j]);
            *(s16x4*)&sT[wid][wrow * 72 + ct * 16 + q4] = pv;
        }
        asm volatile("s_waitcnt lgkmcnt(0)" ::: "memory");
        if (rbase + 16 <= (long)n) {
            #pragma unroll
            for (int s = 0; s < 2; ++s) {
                int f = s * 64 + lane;
                s16x8 v = *(const s16x8*)&sT[wid][(f >> 3) * 72 + ((f & 7) << 3)];
                *(s16x8*)&Y[rbase * 64 + (size_t)f * 8] = v;
            }
        } else {
            #pragma unroll
            for (int s = 0; s < 2; ++s) {
                int f = s * 64 + lane;
                s16x8 v = *(const s16x8*)&sT[wid][(f >> 3) * 72 + ((f & 7) << 3)];
                long g = rbase * 64 + (size_t)f * 8;
                #pragma unroll
                for (int jj = 0; jj < 8; ++jj)
                    if (g + jj < (long)n * 64) Y[g + jj] = (unsigned short)v[jj];
            }
        }
        asm volatile("s_waitcnt lgkmcnt(0)" ::: "memory");
    }
}

// per bucket: histogram + in-LDS exclusive scan of PAD8 degrees. 512 threads.
__global__ __launch_bounds__(512)
void hist_scan(const int* __restrict__ packed, const int* __restrict__ cnts,
               int* __restrict__ degi, int* __restrict__ rowptrP,
               int* __restrict__ partial, int n)
{
    __shared__ int h[512];
    __shared__ int s[256];
    const int b = blockIdx.x, t = threadIdx.x, nb = b << 9;
    int cnt = n - nb; if (cnt > 512) cnt = 512;
    for (int i = t; i < 512; i += 512) h[i] = 0;
    __syncthreads();
    int bs = b * BSTRIDE, be = bs + cnts[b];
    for (int i = bs + t; i < be; i += 512)
        atomicAdd(&h[packed[i] & 511], 1);
    __syncthreads();
    int e0 = 0, e1 = 0, p0 = 0, p1 = 0, mysum = 0;
    if (t < 256) {
        e0 = (2 * t     < cnt) ? h[2 * t]     : 0;
        e1 = (2 * t + 1 < cnt) ? h[2 * t + 1] : 0;
        p0 = (e0 + 7) & ~7;
        p1 = (e1 + 7) & ~7;
        mysum = p0 + p1;
        s[t] = mysum;
    }
    __syncthreads();
    for (int off = 1; off < 256; off <<= 1) {
        int u = (t >= off && t < 256) ? s[t - off] : 0;
        __syncthreads();
        if (t < 256) s[t] += u;
        __syncthreads();
    }
    if (t < 256) {
        int excl = s[t] - mysum;
        if (2 * t < cnt)     { degi[nb + 2 * t]     = e0; rowptrP[nb + 2 * t]     = excl; }
        if (2 * t + 1 < cnt) { degi[nb + 2 * t + 1] = e1; rowptrP[nb + 2 * t + 1] = excl + p0; }
        if (t == 255) partial[b] = s[255];
    }
}

// fill + finalize (512 threads): bucket prefix via cooperative sum, add to
// rowptrP (write back), fill csr, dummy-pad, rowptrP[n], zero dummy feat row.
__global__ __launch_bounds__(512)
void bucket_fill_final(const int* __restrict__ packed, const int* __restrict__ cnts,
                       const int* __restrict__ partial, int* __restrict__ rowptrP,
                       int* __restrict__ csr, unsigned* __restrict__ Adummy,
                       int n, int nbkt, int dummyOff)
{
    __shared__ int cur[512];
    __shared__ int rs[513];
    __shared__ int red[512];
    const int b = blockIdx.x, t = threadIdx.x, nb = b << 9;
    int cnt = n - nb; if (cnt > 512) cnt = 512;

    int loc = 0;
    for (int j = t; j < b; j += 512) loc += partial[j];
    red[t] = loc;
    __syncthreads();
    for (int off = 256; off > 0; off >>= 1) {
        if (t < off) red[t] += red[t + off];
        __syncthreads();
    }
    const int base = red[0];
    const int bend = base + partial[b];

    for (int i = t; i < cnt; i += 512) {
        int v = rowptrP[nb + i] + base;
        rowptrP[nb + i] = v;
        cur[i] = v;
        rs[i] = v;
    }
    if (t == 0) rs[cnt] = bend;
    if (b == nbkt - 1 && t == 0) rowptrP[n] = bend;
    if (b == 0 && t < 32) Adummy[t] = 0u;
    __syncthreads();

    int bs = b * BSTRIDE, be = bs + cnts[b];
    for (int i = bs + t; i < be; i += 512) {
        int p = packed[i];
        int pos = atomicAdd(&cur[p & 511], 1);
        csr[pos] = (p >> 9) << 7;
    }
    __syncthreads();
    for (int i = t; i < cnt; i += 512) {
        int end = rs[i + 1];
        for (int p = cur[i]; p < end; ++p) csr[p] = dummyOff;
    }
}

// ---- pull + fused epilogue, PAD-8 lists, pipelined offsets, 2 rows/wave ----
__global__ __launch_bounds__(256)
void pull_agg_pad(const unsigned short* __restrict__ feat, const int* __restrict__ rowptrP,
                  const int* __restrict__ degi, const int* __restrict__ csrB,
                  const unsigned short* __restrict__ C, const float* __restrict__ bias,
                  unsigned short* __restrict__ H, int n)
{
    const int lane = threadIdx.x & 63;
    const int half = lane >> 5;
    const int c    = lane & 31;
    const int wid  = threadIdx.x >> 6;
    const char* fb = (const char*)feat;
    const int cb   = c << 2;
    const float2 bv = *(const float2*)&bias[c * 2];

    const long w  = (long)blockIdx.x * 4 + wid;
    const long nw = (long)gridDim.x * 4;
    for (long rp = w * 2; rp < n; rp += nw * 2) {
        int2 rr = *(const int2*)&rowptrP[rp];
        int eB = (rp + 1 < n) ? rowptrP[rp + 2] : rr.y;

        const long r = rp + half;
        int dg = 1; unsigned cu = 0;
        if (r < n) {
            dg = degi[r];
            cu = *(const unsigned*)&C[(size_t)r * 64 + (c << 1)];
        }

        int iA = rr.x + (half << 2);
        int iB = rr.y + (half << 2);
        const int endA = rr.y, endB = eB;
        bool dA = iA < endA, dB = iB < endB;
        int4 oA = (int4)(0), oB = (int4)(0);
        if (dA) oA = *(const int4*)&csrB[iA];
        if (dB) oB = *(const int4*)&csrB[iB];

        float a0A = 0.f, a1A = 0.f, a0B = 0.f, a1B = 0.f;
        while (dA | dB) {
            unsigned uA0, uA1, uA2, uA3, uB0, uB1, uB2, uB3;
            if (dA) {
                uA0 = *(const unsigned*)(fb + oA.x + cb);
                uA1 = *(const unsigned*)(fb + oA.y + cb);
                uA2 = *(const unsigned*)(fb + oA.z + cb);
                uA3 = *(const unsigned*)(fb + oA.w + cb);
            }
            if (dB) {
                uB0 = *(const unsigned*)(fb + oB.x + cb);
                uB1 = *(const unsigned*)(fb + oB.y + cb);
                uB2 = *(const unsigned*)(fb + oB.z + cb);
                uB3 = *(const unsigned*)(fb + oB.w + cb);
            }
            int niA = iA + 8, niB = iB + 8;
            bool ndA = niA < endA, ndB = niB < endB;
            int4 tA = oA, tB = oB;
            if (ndA) tA = *(const int4*)&csrB[niA];
            if (ndB) tB = *(const int4*)&csrB[niB];
            if (dA) {
                a0A += bflo(uA0); a1A += bfhi(uA0);
                a0A += bflo(uA1); a1A += bfhi(uA1);
                a0A += bflo(uA2); a1A += bfhi(uA2);
                a0A += bflo(uA3); a1A += bfhi(uA3);
            }
            if (dB) {
                a0B += bflo(uB0); a1B += bfhi(uB0);
                a0B += bflo(uB1); a1B += bfhi(uB1);
                a0B += bflo(uB2); a1B += bfhi(uB2);
                a0B += bflo(uB3); a1B += bfhi(uB3);
            }
            oA = tA; oB = tB; iA = niA; iB = niB; dA = ndA; dB = ndB;
        }

        a0A += __shfl_xor(a0A, 32, 64);
        a1A += __shfl_xor(a1A, 32, 64);
        a0B += __shfl_xor(a0B, 32, 64);
        a1B += __shfl_xor(a1B, 32, 64);

        if (r < n) {
            float m0 = half ? a0B : a0A;
            float m1 = half ? a1B : a1A;
            float d = (float)dg;
            d = d > 1.f ? d : 1.f;
            float inv = 1.f / d;
            float v0 = m0 * inv + bflo(cu) + bv.x;
            float v1 = m1 * inv + bfhi(cu) + bv.y;
            v0 = v0 > 0.f ? v0 : 0.f;
            v1 = v1 > 0.f ? v1 : 0.f;
            unsigned pv = (unsigned)f2bf(v0) | ((unsigned)f2bf(v1) << 16);
            *(unsigned*)&H[(size_t)r * 64 + (c << 1)] = pv;
        }
    }
}

// ---------------- layer-2 GEMM + output GEMM ----------------

__global__ __launch_bounds__(512)
void dual_gemm_b16in(const unsigned short* __restrict__ X, const short* __restrict__ PH,
                     const short* __restrict__ PL, unsigned short* __restrict__ Yl,
                     unsigned short* __restrict__ Yr, int n)
{
    constexpr int NKT = 2;
    __shared__ unsigned short sT[8][16 * 72];
    const int lane = threadIdx.x & 63;
    const int wid  = threadIdx.x >> 6;
    const long ntile = ((long)n + 15) >> 4;
    long t = (long)blockIdx.x * 8 + wid;
    if (t >= ntile) return;
    const long rbase = t << 4;
    long arow = rbase + (lane & 15);
    if (arow >= n) arow = n - 1;
    const int koff = (lane >> 4) << 3;
    const unsigned short* xr = X + arow * 64 + koff;

    s16x8 Bv[NKT];
    #pragma unroll
    for (int kt = 0; kt < NKT; ++kt) Bv[kt] = *(const s16x8*)(xr + kt * 32);

    f32x4 acc[2][4];
    #pragma unroll
    for (int m = 0; m < 2; ++m)
        #pragma unroll
        for (int ct = 0; ct < 4; ++ct) acc[m][ct] = (f32x4)(0.f);

    #pragma unroll
    for (int m = 0; m < 2; ++m)
    #pragma unroll
    for (int ct = 0; ct < 4; ++ct)
    #pragma unroll
    for (int kt = 0; kt < NKT; ++kt) {
        const int fidx = ((((m << 2) | ct) * NKT) + kt) * 64 + lane;
        s16x8 Ah = *(const s16x8*)(PH + (size_t)fidx * 8);
        s16x8 Al = *(const s16x8*)(PL + (size_t)fidx * 8);
        acc[m][ct] = __builtin_amdgcn_mfma_f32_16x16x32_bf16(Ah, Bv[kt], acc[m][ct], 0, 0, 0);
        acc[m][ct] = __builtin_amdgcn_mfma_f32_16x16x32_bf16(Al, Bv[kt], acc[m][ct], 0, 0, 0);
    }

    const int wrow = lane & 15, q4 = (lane >> 4) << 2;
    #pragma unroll
    for (int m = 0; m < 2; ++m) {
        unsigned short* __restrict__ Y = m ? Yr : Yl;
        #pragma unroll
        for (int ct = 0; ct < 4; ++ct) {
            s16x4 pv;
            #pragma unroll
            for (int j = 0; j < 4; ++j) pv[j] = (short)f2bf(acc[m][ct][j]);
            *(s16x4*)&sT[wid][wrow * 72 + ct * 16 + q4] = pv;
        }
        asm volatile("s_waitcnt lgkmcnt(0)" ::: "memory");
        if (rbase + 16 <= (long)n) {
            #pragma unroll
            for (int s = 0; s < 2; ++s) {
                int f = s * 64 + lane;
                s16x8 v = *(const s16x8*)&sT[wid][(f >> 3) * 72 + ((f & 7) << 3)];
                *(s16x8*)&Y[rbase * 64 + (size_t)f * 8] = v;
            }
        } else {
            #pragma unroll
            for (int s = 0; s < 2; ++s) {
                int f = s * 64 + lane;
                s16x8 v = *(const s16x8*)&sT[wid][(f >> 3) * 72 + ((f & 7) << 3)];
                long g = rbase * 64 + (size_t)f * 8;
                #pragma unroll
                for (int jj = 0; jj < 8; ++jj)
                    if (g + jj < (long)n * 64) Y[g + jj] = (unsigned short)v[jj];
            }
        }
        asm volatile("s_waitcnt lgkmcnt(0)" ::: "memory");
    }
}

// out = H2@Wo + bo. 256-thread blocks (4 waves, 30KB LDS -> 5 blocks/CU).
__global__ __launch_bounds__(256)
void gemm_out_mfma(const unsigned short* __restrict__ X, const short* __restrict__ PH,
                   const short* __restrict__ PL, const float* __restrict__ bo,
                   float* __restrict__ Y, int n)
{
    constexpr int NCT = 7;
    __shared__ float sT[4][16 * 120];    // 30 KB
    const int lane = threadIdx.x & 63;
    const int wid  = threadIdx.x >> 6;
    const long ntile = ((long)n + 15) >> 4;
    long t = (long)blockIdx.x * 4 + wid;
    if (t >= ntile) return;
    const long rbase = t << 4;
    long arow = rbase + (lane & 15);
    if (arow >= n) arow = n - 1;
    const int koff = (lane >> 4) << 3;
    const unsigned short* xr = X + arow * 64 + koff;

    s16x8 Bv[2];
    #pragma unroll
    for (int kt = 0; kt < 2; ++kt) Bv[kt] = *(const s16x8*)(xr + kt * 32);

    f32x4 acc[NCT];
    #pragma unroll
    for (int ct = 0; ct < NCT; ++ct) acc[ct] = (f32x4)(0.f);

    #pragma unroll
    for (int ct = 0; ct < NCT; ++ct)
    #pragma unroll
    for (int kt = 0; kt < 2; ++kt) {
        const int fidx = (ct * 2 + kt) * 64 + lane;
        s16x8 Ah = *(const s16x8*)(PH + (size_t)fidx * 8);
        s16x8 Al = *(const s16x8*)(PL + (size_t)fidx * 8);
        acc[ct] = __builtin_amdgcn_mfma_f32_16x16x32_bf16(Ah, Bv[kt], acc[ct], 0, 0, 0);
        acc[ct] = __builtin_amdgcn_mfma_f32_16x16x32_bf16(Al, Bv[kt], acc[ct], 0, 0, 0);
    }

    const int wrow = lane & 15, q4 = (lane >> 4) << 2;
    #pragma unroll
    for (int ct = 0; ct < NCT; ++ct)
        *(f32x4*)&sT[wid][wrow * 120 + ct * 16 + q4] = acc[ct];
    asm volatile("s_waitcnt lgkmcnt(0)" ::: "memory");

    if (rbase + 16 <= (long)n) {
        #pragma unroll
        for (int s = 0; s < 7; ++s) {
            int f = s * 64 + lane;
            int row = f / 28, ch = f % 28;
            f32x4 v = *(const f32x4*)&sT[wid][row * 120 + ch * 4];
            f32x4 b4 = *(const f32x4*)&bo[ch * 4];
            v.x += b4.x; v.y += b4.y; v.z += b4.z; v.w += b4.w;
            *(f32x4*)&Y[rbase * 112 + (size_t)f * 4] = v;
        }
    } else {
        #pragma unroll
        for (int s = 0; s < 7; ++s) {
            int f = s * 64 + lane;
            int row = f / 28, ch = f % 28;
            f32x4 v = *(const f32x4*)&sT[wid][row * 120 + ch * 4];
            #pragma unroll
            for (int jj = 0; jj < 4; ++jj) {
                long g = rbase * 112 + (size_t)f * 4 + jj;
                if (g < (long)n * 112) Y[g] = v[jj] + bo[ch * 4 + jj];
            }
        }
    }
}

// ---------------- launch ----------------

extern "C" void kernel_launch(void* const* d_in, const int* in_sizes, int n_in,
                              void* d_out, int out_size, void* d_ws, size_t ws_size,
                              hipStream_t stream)
{
    const float* x   = (const float*)d_in[0];
    const int*   ei  = (const int*)d_in[1];
    const float* W1l = (const float*)d_in[2];
    const float* b1  = (const float*)d_in[3];
    const float* W1r = (const float*)d_in[4];
    const float* W2l = (const float*)d_in[5];
    const float* b2  = (const float*)d_in[6];
    const float* W2r = (const float*)d_in[7];
    const float* Wo  = (const float*)d_in[8];
    const float* bo  = (const float*)d_in[9];
    float* out = (float*)d_out;

    const int n = in_sizes[0] / 128;
    const int E = in_sizes[1] / 2;
    const int* srcI = ei;
    const int* dstI = ei + E;
    const int nbkt   = (n + 511) >> 9;
    const size_t nn64 = (size_t)n * 64;
    const size_t csrCap = (size_t)E + (size_t)8 * n + 16;   // pad-8 capacity

    unsigned short* A = (unsigned short*)d_ws;    // (n+1)*64 bf16 (row n = dummy)
    unsigned short* C = A + nn64 + 64;            // n*64
    unsigned short* H = C + nn64;                 // n*64
    int*   rowptrP= (int*)(H + nn64);             // n+1
    int*   degi   = rowptrP + n + 1;              // n
    int*   partial= degi + n;                     // 260
    int*   csr    = partial + 260;                // csrCap (byte offsets)
    int*   packed = csr + csrCap;                 // nbkt * BSTRIDE
    int*   gcursor= packed + (size_t)nbkt * BSTRIDE;  // nbkt (per-bucket counts)
    short* PH1    = (short*)(gcursor + nbkt);     // 16384
    short* PL1    = PH1 + 16384;
    short* PH2    = PL1 + 16384;                  // 8192
    short* PL2    = PH2 + 8192;
    short* PHo    = PL2 + 8192;                   // 7168
    short* PLo    = PHo + 7168;

    const long ntile = ((long)n + 15) >> 4;
    const int gmf  = (int)((ntile + 7) / 8);
    const int gout = (int)((ntile + 3) / 4);
    const int sctBlocks = (int)((E + 8191) / 8192);

    // ---- prep (gcursor zeroed inside pack_frags) ----
    pack_frags<<<16, 256, 0, stream>>>(W1l, W1r, W2l, W2r, Wo,
                                       PH1, PL1, PH2, PL2, PHo, PLo, gcursor, nbkt);

    // ---- scatter (fixed-stride buckets, first in grid) overlapped with GEMM1 ----
    fused_gemm1_scatter<<<sctBlocks + gmf, 512, 0, stream>>>(
        x, PH1, PL1, A, C, n, srcI, dstI, gcursor, packed, E, nbkt, sctBlocks);

    // ---- CSR build: hist+scan -> fill+finalize (prefix computed in-kernel) ----
    hist_scan<<<nbkt, 512, 0, stream>>>(packed, gcursor, degi, rowptrP, partial, n);
    bucket_fill_final<<<nbkt, 512, 0, stream>>>(packed, gcursor, partial, rowptrP,
                                                csr, (unsigned*)(A + nn64), n, nbkt, n << 7);

    // ---- layer 1 aggregation ----
    pull_agg_pad<<<4096, 256, 0, stream>>>(A, rowptrP, degi, csr, C, b1, H, n);

    // ---- layer 2 ----
    dual_gemm_b16in<<<gmf, 512, 0, stream>>>(H, PH2, PL2, A, C, n);
    pull_agg_pad<<<4096, 256, 0, stream>>>(A, rowptrP, degi, csr, C, b2, H, n);

    // ---- output projection ----
    gemm_out_mfma<<<gout, 256, 0, stream>>>(H, PHo, PLo, bo, out, n);
}